// Round 3
// baseline (202.852 us; speedup 1.0000x reference)
//
#include <hip/hip_runtime.h>

// OrthogonalLinear: pyramid Givens circuit, n = m = 512, B = 256.
// T = 1021 layers; layer t has gates (i, i+1) for i = (t&1), (t&1)+2, ...,
// i <= min(t, 1020-t). theta index: k = (t+i)/2 + 1, idx = k(k-1)/2 + (k-1-i).
//
// Table W (d_ws): 510 pair-blocks of 512 float2 (c,s) slots, slot r within
// pair p at float2 index p*512 + r, where r = L*8 + h*4 + j encodes
// lane L (0..63), parity h (0=even layer t=2p, 1=odd t=2p+1), gate j (0..3)
// at wire i = 8L + 2j + h. Then 256 float2 for the final layer t=1020
// (e = L*4 + j, wire i = 8L + 2j). Total 261376 float2 = ~2.09 MB.
//
// circuit_kernel: block = 128 threads = 2 waves per row.
//   wave 0 (consumer): row state in registers (8 wires/lane), Givens math.
//   wave 1 (producer): stages chunks of 6 pairs global->VGPR->LDS ring,
//     one chunk ahead; double-buffered LDS, barrier per chunk. This makes
//     the prefetch distance structural (a full chunk of compute) instead of
//     relying on regalloc keeping a register ring alive (R2's failure mode).

#define N_WIRES 512
#define BATCH   256
#define PAIRS   510
#define NPAIR_SLOTS (PAIRS * 512)        // 261120 float2
#define TOTAL_SLOTS (NPAIR_SLOTS + 256)  // 261376 float2
#define FINAL4  130560                   // float4 index of final-layer data
#define CHUNK   6                        // pairs per chunk; 510 = 6*85
#define NCHUNK  85
#define PAIR4   320                      // padded float4 per pair in LDS (64 lanes * 5)
#define BUF4    (CHUNK * PAIR4)          // 1920 float4 per buffer

// ---------------- kernel 1: cos/sin table, coalesced float2 stores ----------
__global__ __launch_bounds__(256) void sincos_kernel(
    const float* __restrict__ thetas, float2* __restrict__ W2) {
  int tid = blockIdx.x * 256 + threadIdx.x;
  if (tid >= TOTAL_SLOTS) return;
  float c = 1.0f, s = 0.0f;
  if (tid < NPAIR_SLOTS) {
    int p = tid >> 9, r = tid & 511;
    int L = r >> 3, h = (r >> 2) & 1, j = r & 3;
    int t = 2 * p + h;
    int i = 8 * L + 2 * j + h;
    if (i <= min(t, 1020 - t)) {
      int k = ((t + i) >> 1) + 1;
      int idx = (k * (k - 1)) / 2 + (k - 1 - i);
      __sincosf(thetas[idx], &s, &c);
    }
  } else {
    int e = tid - NPAIR_SLOTS;
    int L = e >> 2, j = e & 3;
    if (8 * L + 2 * j == 0) __sincosf(thetas[130815], &s, &c);  // last theta
  }
  W2[tid] = make_float2(c, s);
}

// ---------------- kernel 2: apply circuit ----------------
__device__ __forceinline__ void gate(float& a, float& b, float c, float s) {
  float na = fmaf(c, a, s * b);
  float nb = fmaf(c, b, -(s * a));
  a = na;
  b = nb;
}

// q0 = (cE0,sE0,cE1,sE1), q1 = (cE2,sE2,cE3,sE3)
__device__ __forceinline__ void even_layer(float (&v)[8], float4 q0, float4 q1) {
  gate(v[0], v[1], q0.x, q0.y);
  gate(v[2], v[3], q0.z, q0.w);
  gate(v[4], v[5], q1.x, q1.y);
  gate(v[6], v[7], q1.z, q1.w);
}

// q2 = (cO0,sO0,cO1,sO1), q3 = (cO2,sO2,cO3,sO3); gate j at wire 8L+2j+1
__device__ __forceinline__ void odd_layer(float (&v)[8], float4 q2, float4 q3,
                                          int lane) {
  float rv0 = __shfl_down(v[0], 1);   // right neighbor's wire 8L+8 (pre-update)
  float lv7 = __shfl_up(v[7], 1);     // left neighbor's wire 8L-1 (pre-update)
  float cl  = __shfl_up(q3.z, 1);     // left neighbor's boundary gate c
  float sl  = __shfl_up(q3.w, 1);     // left neighbor's boundary gate s
  cl = (lane == 0) ? 1.0f : cl;       // no gate below wire 0
  sl = (lane == 0) ? 0.0f : sl;
  gate(v[1], v[2], q2.x, q2.y);
  gate(v[3], v[4], q2.z, q2.w);
  gate(v[5], v[6], q3.x, q3.y);
  float nv7 = fmaf(q3.z, v[7], q3.w * rv0);  // a-side of gate (8L+7, 8L+8)
  float nv0 = fmaf(cl, v[0], -(sl * lv7));   // b-side of gate (8L-1, 8L)
  v[7] = nv7;
  v[0] = nv0;
}

__global__ __launch_bounds__(128, 1) void circuit_kernel(
    const float* __restrict__ x, const float* __restrict__ W,
    const float* __restrict__ bias, float* __restrict__ out) {
  __shared__ float4 smem[2 * BUF4];   // 61440 B
  const int lane = threadIdx.x & 63;
  const bool is_prod = threadIdx.x >= 64;
  const int row = blockIdx.x;
  const float4* __restrict__ Wg4 = (const float4*)W;

  float v[8];
  float4 D[CHUNK * 4];                // producer ring: 24 float4 = 96 VGPRs
  // LDS write slot for producer lane: within an instr group q, this lane
  // writes record Lr = (q&3)*16 + (lane>>2), quarter qq = lane&3:
  // float4 idx = pr*PAIR4 + (q&3)*80 + (lane>>2)*5 + (lane&3)
  const int b0 = (lane >> 2) * 5 + (lane & 3);

  if (is_prod) {
    // prologue: chunk 0 -> buf 0 (via regs), chunk 1 -> D
#pragma unroll
    for (int q = 0; q < CHUNK * 4; ++q) D[q] = Wg4[q * 64 + lane];
#pragma unroll
    for (int q = 0; q < CHUNK * 4; ++q)
      smem[(q >> 2) * PAIR4 + (q & 3) * 80 + b0] = D[q];
#pragma unroll
    for (int q = 0; q < CHUNK * 4; ++q) D[q] = Wg4[1536 + q * 64 + lane];
  } else {
    const float* xr = x + row * N_WIRES + lane * 8;
    float4 x0 = *(const float4*)(xr);
    float4 x1 = *(const float4*)(xr + 4);
    v[0] = x0.x; v[1] = x0.y; v[2] = x0.z; v[3] = x0.w;
    v[4] = x1.x; v[5] = x1.y; v[6] = x1.z; v[7] = x1.w;
  }
  __syncthreads();

  for (int k = 0; k < NCHUNK; ++k) {
    if (is_prod) {
      if (k + 1 < NCHUNK) {           // write chunk k+1 (in D) to its buffer
        float4* dst = smem + ((k + 1) & 1) * BUF4;
#pragma unroll
        for (int q = 0; q < CHUNK * 4; ++q)
          dst[(q >> 2) * PAIR4 + (q & 3) * 80 + b0] = D[q];
      }
      if (k + 2 < NCHUNK) {           // load chunk k+2 into D
        const float4* src = Wg4 + (k + 2) * (CHUNK * 256) + lane;
#pragma unroll
        for (int q = 0; q < CHUNK * 4; ++q) D[q] = src[q * 64];
      }
    } else {
      const float4* buf = smem + (k & 1) * BUF4 + lane * 5;
#pragma unroll
      for (int pr = 0; pr < CHUNK; ++pr) {
        float4 q0 = buf[pr * PAIR4 + 0];
        float4 q1 = buf[pr * PAIR4 + 1];
        float4 q2 = buf[pr * PAIR4 + 2];
        float4 q3 = buf[pr * PAIR4 + 3];
        even_layer(v, q0, q1);
        odd_layer(v, q2, q3, lane);
      }
    }
    __syncthreads();
  }

  if (!is_prod) {
    // final even layer t = 1020 (only gate i=0 live; table pre-masked)
    float4 f0 = Wg4[FINAL4 + lane * 2];
    float4 f1 = Wg4[FINAL4 + lane * 2 + 1];
    even_layer(v, f0, f1);

    const float* br = bias + lane * 8;
    float4 bi0 = *(const float4*)(br);
    float4 bi1 = *(const float4*)(br + 4);
    float4 o0 = {v[0] + bi0.x, v[1] + bi0.y, v[2] + bi0.z, v[3] + bi0.w};
    float4 o1 = {v[4] + bi1.x, v[5] + bi1.y, v[6] + bi1.z, v[7] + bi1.w};
    float* orow = out + row * N_WIRES + lane * 8;
    *(float4*)(orow) = o0;
    *(float4*)(orow + 4) = o1;
  }
}

extern "C" void kernel_launch(void* const* d_in, const int* in_sizes, int n_in,
                              void* d_out, int out_size, void* d_ws,
                              size_t ws_size, hipStream_t stream) {
  const float* x = (const float*)d_in[0];       // (256, 512) f32
  const float* thetas = (const float*)d_in[1];  // (130816,) f32
  const float* bias = (const float*)d_in[2];    // (512,) f32
  float* out = (float*)d_out;                   // (256, 512) f32

  float* W = (float*)d_ws;                      // 261376 float2 = ~2.09 MB

  sincos_kernel<<<TOTAL_SLOTS / 256, 256, 0, stream>>>(thetas, (float2*)W);
  circuit_kernel<<<BATCH, 128, 0, stream>>>(x, W, bias, out);
}

// Round 4
// 144.797 us; speedup vs baseline: 1.4009x; 1.4009x over previous
//
#include <hip/hip_runtime.h>
#include <stdint.h>

// OrthogonalLinear: pyramid Givens circuit, n = m = 512, B = 256.
// T = 1021 layers; layer t has gates (i, i+1) for i = (t&1), (t&1)+2, ...,
// i <= min(t, 1020-t). theta index: k = (t+i)/2 + 1, idx = k(k-1)/2 + (k-1-i).
//
// Table W4 (d_ws), float4 units: pair p (layers t=2p, 2p+1) occupies
// float4 [p*256, (p+1)*256). Instruction group q in 0..3, lane L:
//   idx = p*256 + q*64 + L holds lane L's record quarter:
//   q0 = (cE0,sE0,cE1,sE1)  even gates at wires 8L+0, 8L+2
//   q1 = (cE2,sE2,cE3,sE3)  even gates at wires 8L+4, 8L+6
//   q2 = (cO0,sO0,cO1,sO1)  odd  gates at wires 8L+1, 8L+3
//   q3 = (cO2,sO2,cO3,sO3)  odd  gates at wires 8L+5, 8L+7
// This order is exactly what global_load_lds produces in LDS (base + lane*16),
// so consumer ds_read_b128 at lane*16 is conflict-free with NO rearrangement.
// Final layer t=1020 at float4 [130560, 130688): e = L*2 + half.
// Total 130688 float4 = 2.09 MB.

#define N_WIRES 512
#define BATCH   256
#define PAIRS   510
#define CHUNK   6                  // pairs per chunk; 510 = 6 * 85
#define NCHUNK  85
#define CHUNK4  (CHUNK * 256)      // 1536 float4 = 24 KB per chunk
#define LOADS_PER_CHUNK (CHUNK * 4)  // 24 global_load_lds per chunk
#define FINAL4  (PAIRS * 256)      // 130560
#define TOTAL4  (FINAL4 + 128)     // 130688

// ---------------- kernel 1: cos/sin table, one float4 store/thread ---------
__device__ __forceinline__ float2 gate_coeff(const float* __restrict__ th,
                                             int t, int i) {
  float c = 1.0f, s = 0.0f;
  if (i <= min(t, 1020 - t)) {
    int k = ((t + i) >> 1) + 1;
    int idx = (k * (k - 1)) / 2 + (k - 1 - i);
    __sincosf(th[idx], &s, &c);
  }
  return make_float2(c, s);
}

__global__ __launch_bounds__(256) void sincos_kernel(
    const float* __restrict__ thetas, float4* __restrict__ W4) {
  int tid = blockIdx.x * 256 + threadIdx.x;
  if (tid >= TOTAL4) return;
  int t, i0;
  if (tid < FINAL4) {
    int p = tid >> 8;
    int r = tid & 255;
    int q = r >> 6;
    int L = r & 63;
    int h = (q >= 2) ? 1 : 0;
    t = 2 * p + h;
    i0 = 8 * L + ((q & 1) ? 4 : 0) + h;
  } else {
    int e = tid - FINAL4;
    int L = e >> 1, half = e & 1;
    t = 1020;
    i0 = 8 * L + 4 * half;
  }
  float2 a = gate_coeff(thetas, t, i0);
  float2 b = gate_coeff(thetas, t, i0 + 2);
  W4[tid] = make_float4(a.x, a.y, b.x, b.y);
}

// ---------------- kernel 2: apply circuit, wave per row ----------------
__device__ __forceinline__ void gate(float& a, float& b, float c, float s) {
  float na = fmaf(c, a, s * b);
  float nb = fmaf(c, b, -(s * a));
  a = na;
  b = nb;
}

__device__ __forceinline__ void even_layer(float (&v)[8], float4 q0, float4 q1) {
  gate(v[0], v[1], q0.x, q0.y);
  gate(v[2], v[3], q0.z, q0.w);
  gate(v[4], v[5], q1.x, q1.y);
  gate(v[6], v[7], q1.z, q1.w);
}

__device__ __forceinline__ void odd_layer(float (&v)[8], float4 q2, float4 q3,
                                          int lane) {
  float rv0 = __shfl_down(v[0], 1);   // right neighbor's wire 8L+8 (post-even)
  float lv7 = __shfl_up(v[7], 1);     // left neighbor's wire 8L-1 (post-even)
  float cl  = __shfl_up(q3.z, 1);     // left neighbor's boundary gate c
  float sl  = __shfl_up(q3.w, 1);     // left neighbor's boundary gate s
  cl = (lane == 0) ? 1.0f : cl;       // no gate below wire 0
  sl = (lane == 0) ? 0.0f : sl;
  gate(v[1], v[2], q2.x, q2.y);
  gate(v[3], v[4], q2.z, q2.w);
  gate(v[5], v[6], q3.x, q3.y);
  float nv7 = fmaf(q3.z, v[7], q3.w * rv0);  // a-side of gate (8L+7, 8L+8)
  float nv0 = fmaf(cl, v[0], -(sl * lv7));   // b-side of gate (8L-1, 8L)
  v[7] = nv7;
  v[0] = nv0;
}

__device__ __forceinline__ void issue_chunk(const float4* __restrict__ Wg,
                                            float4* lds_base, int c, int bsel,
                                            int lane) {
  const float4* src = Wg + c * CHUNK4 + lane;  // per-lane global addr
  float4* dst = lds_base + bsel * CHUNK4;      // wave-uniform LDS base
#pragma unroll
  for (int q = 0; q < LOADS_PER_CHUNK; ++q) {
    __builtin_amdgcn_global_load_lds(
        (__attribute__((address_space(1))) uint32_t*)(src + q * 64),
        (__attribute__((address_space(3))) uint32_t*)(dst + q * 64),
        16, 0, 0);
  }
}

__global__ __launch_bounds__(64, 1) void circuit_kernel(
    const float* __restrict__ x, const float* __restrict__ W,
    const float* __restrict__ bias, float* __restrict__ out) {
  __shared__ float4 lds[2 * CHUNK4];   // 49152 B
  const int lane = threadIdx.x;
  const int row = blockIdx.x;
  const float4* __restrict__ Wg = (const float4*)W;

  const float* xr = x + row * N_WIRES + lane * 8;
  float4 x0 = *(const float4*)(xr);
  float4 x1 = *(const float4*)(xr + 4);
  float v[8] = {x0.x, x0.y, x0.z, x0.w, x1.x, x1.y, x1.z, x1.w};

  // DMA pipeline: chunk k resident while k+1 arrives and k+2 issues.
  issue_chunk(Wg, lds, 0, 0, lane);
  issue_chunk(Wg, lds, 1, 1, lane);

  for (int k = 0; k < NCHUNK; ++k) {
    if (k + 1 < NCHUNK) {
      // wait for chunk k's 24 loads (chunk k+1's 24 may stay in flight)
      asm volatile("s_waitcnt vmcnt(24)" ::: "memory");
    } else {
      asm volatile("s_waitcnt vmcnt(0)" ::: "memory");
    }
    const float4* buf = lds + (k & 1) * CHUNK4;
#pragma unroll
    for (int pr = 0; pr < CHUNK; ++pr) {
      float4 q0 = buf[(pr * 4 + 0) * 64 + lane];
      float4 q1 = buf[(pr * 4 + 1) * 64 + lane];
      float4 q2 = buf[(pr * 4 + 2) * 64 + lane];
      float4 q3 = buf[(pr * 4 + 3) * 64 + lane];
      even_layer(v, q0, q1);
      odd_layer(v, q2, q3, lane);
    }
    if (k + 2 < NCHUNK) issue_chunk(Wg, lds, k + 2, k & 1, lane);
  }

  // final even layer t = 1020 (table pre-masked to identity except gate 0)
  float4 f0 = Wg[FINAL4 + lane * 2];
  float4 f1 = Wg[FINAL4 + lane * 2 + 1];
  even_layer(v, f0, f1);

  const float* br = bias + lane * 8;
  float4 b0 = *(const float4*)(br);
  float4 b1 = *(const float4*)(br + 4);
  float4 o0 = {v[0] + b0.x, v[1] + b0.y, v[2] + b0.z, v[3] + b0.w};
  float4 o1 = {v[4] + b1.x, v[5] + b1.y, v[6] + b1.z, v[7] + b1.w};
  float* orow = out + row * N_WIRES + lane * 8;
  *(float4*)(orow) = o0;
  *(float4*)(orow + 4) = o1;
}

extern "C" void kernel_launch(void* const* d_in, const int* in_sizes, int n_in,
                              void* d_out, int out_size, void* d_ws,
                              size_t ws_size, hipStream_t stream) {
  const float* x = (const float*)d_in[0];       // (256, 512) f32
  const float* thetas = (const float*)d_in[1];  // (130816,) f32
  const float* bias = (const float*)d_in[2];    // (512,) f32
  float* out = (float*)d_out;                   // (256, 512) f32

  float* W = (float*)d_ws;                      // 130688 float4 = 2.09 MB

  sincos_kernel<<<(TOTAL4 + 255) / 256, 256, 0, stream>>>(thetas, (float4*)W);
  circuit_kernel<<<BATCH, 64, 0, stream>>>(x, W, bias, out);
}